// Round 4
// baseline (1083.440 us; speedup 1.0000x reference)
//
#include <hip/hip_runtime.h>
#include <hip/hip_fp16.h>
#include <cstdint>

typedef _Float16 f16;
typedef _Float16 f16x8 __attribute__((ext_vector_type(8)));
typedef float f32x4 __attribute__((ext_vector_type(4)));

#define MFMA16(a, b, c) __builtin_amdgcn_mfma_f32_16x16x32_f16(a, b, c, 0, 0, 0)

constexpr int Lq = 1024, Nb = 8, Cc = 1024, Hh = 16, Dd = 64;
constexpr int Mrows = Lq * Nb;            // 8192
constexpr float LOG100 = 4.6051701859880913680f;

// ---------- async global->LDS, 16B per lane ----------
typedef const __attribute__((address_space(1))) unsigned int* gu32p;
typedef __attribute__((address_space(3))) unsigned int* lu32p;
__device__ __forceinline__ void gl_lds16(const void* g, void* l) {
  __builtin_amdgcn_global_load_lds((gu32p)g, (lu32p)l, 16, 0, 0);
}

// ---------- f32 -> f16 convert, 8 elems/thread ----------
__global__ __launch_bounds__(256) void k_cvt(const float* __restrict__ in,
                                             f16* __restrict__ out, int n8) {
  int i = blockIdx.x * blockDim.x + threadIdx.x;
  if (i >= n8) return;
  const float4* p = (const float4*)in + (size_t)i * 2;
  float4 a = p[0], b = p[1];
  f16x8 o = {(f16)a.x, (f16)a.y, (f16)a.z, (f16)a.w,
             (f16)b.x, (f16)b.y, (f16)b.z, (f16)b.w};
  *((f16x8*)out + i) = o;
}

// ---------- generic fp16 GEMM: C = A @ B^T + bias ----------
// A: [M][Kd] fp16 row-major, B: [Np][Kd] fp16 row-major (contraction innermost)
// 128x128 tile, 4 waves (2x2), each wave 64x64 = 4x4 MFMA 16x16x32 tiles.
// LDS layout: 16B chunks stored in exact fragment-read order (chunk-linear):
//   chunk index c = g*64 + kc*16 + r  (g=row-group of 16, kc=k-chunk of 8 f16, r=row%16)
// so a wave's ds_read_b128 at (group*1024 + lane*16) is perfectly linear.
template <typename OutT>
__global__ __launch_bounds__(256) void k_gemm(const f16* __restrict__ A,
                                              const f16* __restrict__ B,
                                              const float* __restrict__ bias,
                                              OutT* __restrict__ Co,
                                              int Np, int Kd) {
  __shared__ f16 Ash[128 * 32];
  __shared__ f16 Bsh[128 * 32];
  const int tid = threadIdx.x, lane = tid & 63, wid = tid >> 6;
  const int m0 = blockIdx.y * 128, n0 = blockIdx.x * 128;
  const int wy = wid >> 1, wx = wid & 1;
  const int rq = lane & 15, kq = lane >> 4;
  f32x4 acc[4][4] = {};
  const int nkt = Kd >> 5;
  for (int kt = 0; kt < nkt; ++kt) {
    __syncthreads();  // protect LDS reuse from previous iteration's reads
    // stage 512 chunks of A and of B (2 issues/wave each)
    for (int b2 = 0; b2 < 2; ++b2) {
      int cbase = (b2 * 4 + wid) * 64;  // wave-uniform
      int c = cbase + lane;
      int g = c >> 6, kc = (c >> 4) & 3, r = c & 15;
      int colh = kt * 32 + kc * 8;
      gl_lds16(A + (size_t)(m0 + g * 16 + r) * Kd + colh, (char*)Ash + cbase * 16);
      gl_lds16(B + (size_t)(n0 + g * 16 + r) * Kd + colh, (char*)Bsh + cbase * 16);
    }
    __syncthreads();  // drains vmcnt -> LDS tiles complete
    f16x8 af[4], bf[4];
    for (int t = 0; t < 4; ++t)
      af[t] = *(const f16x8*)((const char*)Ash + (((wy * 4 + t) * 64 + lane) * 16));
    for (int u = 0; u < 4; ++u)
      bf[u] = *(const f16x8*)((const char*)Bsh + (((wx * 4 + u) * 64 + lane) * 16));
    for (int t = 0; t < 4; ++t)
      for (int u = 0; u < 4; ++u)
        acc[t][u] = MFMA16(af[t], bf[u], acc[t][u]);
  }
  // epilogue: D layout col=lane&15, row=(lane>>4)*4+reg
  for (int t = 0; t < 4; ++t) {
    int row = m0 + wy * 64 + t * 16 + 4 * kq;
    for (int u = 0; u < 4; ++u) {
      int col = n0 + wx * 64 + u * 16 + rq;
      float bv = bias[col];
      for (int rr = 0; rr < 4; ++rr) {
        float v = acc[t][u][rr] + bv;
        Co[(size_t)(row + rr) * Np + col] = (OutT)v;
      }
    }
  }
}

// ---------- normalize q,k per head + head layout; transpose v ----------
// qkv: [8192][3072] fp16 (rows = l*N+n). Outputs:
//   qhat/khat: [128][1024][64] fp16 (B=n*H+h), vT: [128][64][1024] fp16
__global__ __launch_bounds__(256) void k_norm(const f16* __restrict__ qkv,
                                              f16* __restrict__ qhat,
                                              f16* __restrict__ khat,
                                              f16* __restrict__ vTt) {
  __shared__ f16 vt[64][72];
  const int blk = blockIdx.x;
  const int b = blk >> 4, lc = blk & 15;
  const int h = b & 15, n = b >> 4;
  const int tid = threadIdx.x;
  const int g4 = tid >> 2, sub = tid & 3;  // 4 lanes per row, 16 f16 each
  const int lrow = lc * 64 + g4;
  const size_t srow = ((size_t)lrow * Nb + n) * 3072;
  for (int qk = 0; qk < 2; ++qk) {
    const f16* p = qkv + srow + qk * 1024 + h * 64 + sub * 16;
    f16x8 a = *(const f16x8*)p;
    f16x8 c2 = *(const f16x8*)(p + 8);
    float ss = 0.f;
    for (int e = 0; e < 8; ++e) { float x = (float)a[e]; ss += x * x; }
    for (int e = 0; e < 8; ++e) { float x = (float)c2[e]; ss += x * x; }
    ss += __shfl_xor(ss, 1);
    ss += __shfl_xor(ss, 2);
    float sc = 1.f / fmaxf(sqrtf(ss), 1e-12f);
    f16x8 oa, ob;
    for (int e = 0; e < 8; ++e) oa[e] = (f16)((float)a[e] * sc);
    for (int e = 0; e < 8; ++e) ob[e] = (f16)((float)c2[e] * sc);
    f16* dst = (qk ? khat : qhat) + ((size_t)b * Lq + lrow) * Dd + sub * 16;
    *(f16x8*)dst = oa;
    *(f16x8*)(dst + 8) = ob;
  }
  {
    const f16* p = qkv + srow + 2048 + h * 64 + sub * 16;
    f16x8 a = *(const f16x8*)p;
    f16x8 c2 = *(const f16x8*)(p + 8);
    for (int e = 0; e < 8; ++e) vt[g4][sub * 16 + e] = a[e];
    for (int e = 0; e < 8; ++e) vt[g4][sub * 16 + 8 + e] = c2[e];
  }
  __syncthreads();
  {
    const int d = g4;
    f16x8 oa, ob;
    for (int e = 0; e < 8; ++e) oa[e] = vt[sub * 16 + e][d];
    for (int e = 0; e < 8; ++e) ob[e] = vt[sub * 16 + 8 + e][d];
    f16* dst = vTt + ((size_t)b * Dd + d) * Lq + lc * 64 + sub * 16;
    *(f16x8*)dst = oa;
    *(f16x8*)(dst + 8) = ob;
  }
}

// ---------- two-pass flash attention with exact softmax write ----------
// block = 256 thr = 4 waves; block handles (b, 64 q-rows); wave = 16 q-rows.
__global__ __launch_bounds__(256) void k_attn(const f16* __restrict__ qhat,
                                              const f16* __restrict__ khat,
                                              const f16* __restrict__ vTt,
                                              const float* __restrict__ lsc,
                                              const float* __restrict__ hsc,
                                              float* __restrict__ attn,
                                              f16* __restrict__ Ows) {
  __shared__ float plds[4][16 * 68];  // per-wave P tile, stride 68 (bank-safe)
  const int blk = blockIdx.x;
  const int b = blk >> 4, qc = blk & 15;
  const int h = b & 15, n = b >> 4;
  const int tid = threadIdx.x, lane = tid & 63, w = tid >> 6;
  const int rq = lane & 15, kq = lane >> 4;
  const int ib = qc * 64 + w * 16;
  const float ls = __expf(fminf(lsc[h], LOG100));
  const float hs = hsc[h];
  const f16* qb = qhat + ((size_t)b * Lq + ib) * Dd;
  f16x8 qf0 = *(const f16x8*)(qb + (size_t)rq * Dd + kq * 8);
  f16x8 qf1 = *(const f16x8*)(qb + (size_t)rq * Dd + 32 + kq * 8);
  const f16* kb = khat + (size_t)b * Lq * Dd;
  float m[4], l[4];
  for (int rr = 0; rr < 4; ++rr) { m[rr] = -3e38f; l[rr] = 0.f; }
  // ---- pass 1: online row max + sumexp ----
  for (int kt = 0; kt < 16; ++kt) {
    const int j0 = kt * 64;
    f32x4 s[4];
    for (int u = 0; u < 4; ++u) {
      const f16* kp = kb + (size_t)(j0 + u * 16 + rq) * Dd + kq * 8;
      f16x8 k0 = *(const f16x8*)kp;
      f16x8 k1 = *(const f16x8*)(kp + 32);
      f32x4 a = {0.f, 0.f, 0.f, 0.f};
      a = MFMA16(qf0, k0, a);
      a = MFMA16(qf1, k1, a);
      s[u] = a;
    }
    for (int rr = 0; rr < 4; ++rr) {
      float v0 = s[0][rr] * ls, v1 = s[1][rr] * ls;
      float v2 = s[2][rr] * ls, v3 = s[3][rr] * ls;
      float c = fmaxf(fmaxf(v0, v1), fmaxf(v2, v3));
      c = fmaxf(c, __shfl_xor(c, 1));
      c = fmaxf(c, __shfl_xor(c, 2));
      c = fmaxf(c, __shfl_xor(c, 4));
      c = fmaxf(c, __shfl_xor(c, 8));
      float mn = fmaxf(m[rr], c);
      float sum = __expf(v0 - mn) + __expf(v1 - mn) + __expf(v2 - mn) + __expf(v3 - mn);
      sum += __shfl_xor(sum, 1);
      sum += __shfl_xor(sum, 2);
      sum += __shfl_xor(sum, 4);
      sum += __shfl_xor(sum, 8);
      l[rr] = l[rr] * __expf(m[rr] - mn) + sum;
      m[rr] = mn;
    }
  }
  float invl[4];
  for (int rr = 0; rr < 4; ++rr) invl[rr] = 1.f / l[rr];
  // ---- pass 2: recompute S, write exact softmax, accumulate PV ----
  float* pw = plds[w];
  f32x4 Oa[4] = {};
  const f16* vb = vTt + (size_t)b * Dd * Lq;
  float* ab = attn + (size_t)b * Lq * Lq;
  for (int kt = 0; kt < 16; ++kt) {
    const int j0 = kt * 64;
    f32x4 s[4];
    for (int u = 0; u < 4; ++u) {
      const f16* kp = kb + (size_t)(j0 + u * 16 + rq) * Dd + kq * 8;
      f16x8 k0 = *(const f16x8*)kp;
      f16x8 k1 = *(const f16x8*)(kp + 32);
      f32x4 a = {0.f, 0.f, 0.f, 0.f};
      a = MFMA16(qf0, k0, a);
      a = MFMA16(qf1, k1, a);
      s[u] = a;
    }
    for (int u = 0; u < 4; ++u) {
      for (int rr = 0; rr < 4; ++rr) {
        float p = __expf(s[u][rr] * ls - m[rr]) * invl[rr];
        int irow = 4 * kq + rr;
        ab[(size_t)(ib + irow) * Lq + j0 + u * 16 + rq] = p;
        pw[irow * 68 + u * 16 + rq] = p;
      }
    }
    // per-wave private LDS round-trip: D-layout -> A-fragment layout
    f16x8 pa[2];
    for (int ks = 0; ks < 2; ++ks) {
      const float* sp = pw + rq * 68 + ks * 32 + kq * 8;
      f16x8 t;
      for (int e = 0; e < 8; ++e) t[e] = (f16)sp[e];
      pa[ks] = t;
    }
    for (int t = 0; t < 4; ++t) {
      const f16* vp = vb + (size_t)(t * 16 + rq) * Lq + j0 + kq * 8;
      f16x8 v0 = *(const f16x8*)vp;
      f16x8 v1 = *(const f16x8*)(vp + 32);
      Oa[t] = MFMA16(pa[0], v0, Oa[t]);
      Oa[t] = MFMA16(pa[1], v1, Oa[t]);
    }
  }
  // epilogue: apply head_scale, store O in (L, N, C) fp16 layout
  for (int t = 0; t < 4; ++t) {
    for (int rr = 0; rr < 4; ++rr) {
      int iseq = ib + 4 * kq + rr;
      int d = t * 16 + rq;
      Ows[((size_t)iseq * Nb + n) * Cc + h * Dd + d] = (f16)(Oa[t][rr] * hs);
    }
  }
}

extern "C" void kernel_launch(void* const* d_in, const int* in_sizes, int n_in,
                              void* d_out, int out_size, void* d_ws, size_t ws_size,
                              hipStream_t stream) {
  const float* x     = (const float*)d_in[0];
  const float* w_in  = (const float*)d_in[1];
  const float* b_in  = (const float*)d_in[2];
  const float* lsc   = (const float*)d_in[3];
  const float* hsc   = (const float*)d_in[4];
  const float* w_out = (const float*)d_in[5];
  const float* b_out = (const float*)d_in[6];
  float* out  = (float*)d_out;
  float* attn = out + (size_t)Mrows * Cc;  // outputs concatenated: (out, attn)

  char* ws = (char*)d_ws;
  f16* xh   = (f16*)(ws + 0);            // 8192*1024*2   = 16,777,216
  f16* wh   = (f16*)(ws + 16777216);     // 3072*1024*2   =  6,291,456
  f16* wo   = (f16*)(ws + 23068672);     // 1024*1024*2   =  2,097,152
  f16* qkv  = (f16*)(ws + 25165824);     // 8192*3072*2   = 50,331,648
  f16* qhat = (f16*)(ws + 75497472);     // 128*1024*64*2 = 16,777,216
  f16* khat = (f16*)(ws + 92274688);
  f16* vTt  = (f16*)(ws + 109051904);
  f16* Ows  = (f16*)(ws + 125829120);    // 8192*1024*2
  if (ws_size < 142606336ull) return;    // need ~143 MB scratch

  k_cvt<<<(Mrows * Cc / 8 + 255) / 256, 256, 0, stream>>>(x, xh, Mrows * Cc / 8);
  k_cvt<<<(3072 * 1024 / 8 + 255) / 256, 256, 0, stream>>>(w_in, wh, 3072 * 1024 / 8);
  k_cvt<<<(1024 * 1024 / 8 + 255) / 256, 256, 0, stream>>>(w_out, wo, 1024 * 1024 / 8);
  k_gemm<f16><<<dim3(24, 64), 256, 0, stream>>>(xh, wh, b_in, qkv, 3072, 1024);
  k_norm<<<2048, 256, 0, stream>>>(qkv, qhat, khat, vTt);
  k_attn<<<2048, 256, 0, stream>>>(qhat, khat, vTt, lsc, hsc, attn, Ows);
  k_gemm<float><<<dim3(8, 64), 256, 0, stream>>>(Ows, wo, b_out, out, 1024, 1024);
}

// Round 6
// 1068.109 us; speedup vs baseline: 1.0144x; 1.0144x over previous
//
#include <hip/hip_runtime.h>
#include <hip/hip_fp16.h>
#include <cstdint>

typedef _Float16 f16;
typedef _Float16 f16x8 __attribute__((ext_vector_type(8)));
typedef float f32x4 __attribute__((ext_vector_type(4)));

#define MFMA16(a, b, c) __builtin_amdgcn_mfma_f32_16x16x32_f16(a, b, c, 0, 0, 0)

constexpr int Lq = 1024, Nb = 8, Cc = 1024, Hh = 16, Dd = 64;
constexpr int Mrows = Lq * Nb;            // 8192
constexpr float LOG100 = 4.6051701859880913680f;
constexpr float LOG2E = 1.4426950408889634f;

// ---------- async global->LDS, 16B per lane ----------
typedef const __attribute__((address_space(1))) unsigned int* gu32p;
typedef __attribute__((address_space(3))) unsigned int* lu32p;
__device__ __forceinline__ void gl_lds16(const void* g, void* l) {
  __builtin_amdgcn_global_load_lds((gu32p)g, (lu32p)l, 16, 0, 0);
}

// ---------- f32 -> f16 convert, 8 elems/thread ----------
__global__ __launch_bounds__(256) void k_cvt(const float* __restrict__ in,
                                             f16* __restrict__ out, int n8) {
  int i = blockIdx.x * blockDim.x + threadIdx.x;
  if (i >= n8) return;
  const float4* p = (const float4*)in + (size_t)i * 2;
  float4 a = p[0], b = p[1];
  f16x8 o = {(f16)a.x, (f16)a.y, (f16)a.z, (f16)a.w,
             (f16)b.x, (f16)b.y, (f16)b.z, (f16)b.w};
  *((f16x8*)out + i) = o;
}

// ---------- generic fp16 GEMM: C = A @ B^T + bias ----------
// 128x128 tile, BK=64 (2 k-subtiles of 32), 4 waves (2x2).
// LDS chunk-linear layout: chunk c = g*128 + ks*64 + kq*16 + rq
//   (g = 16-row group, ks = 32-col subtile, kq = 8-f16 k-chunk, rq = row%16)
// -> fragment ds_read_b128 at ((g*2+ks)*64 + lane)*16 is perfectly linear.
template <typename OutT>
__global__ __launch_bounds__(256) void k_gemm(const f16* __restrict__ A,
                                              const f16* __restrict__ B,
                                              const float* __restrict__ bias,
                                              OutT* __restrict__ Co,
                                              int Np, int Kd) {
  __shared__ f16 Ash[128 * 64];
  __shared__ f16 Bsh[128 * 64];
  const int tid = threadIdx.x, lane = tid & 63, wid = tid >> 6;
  const int m0 = blockIdx.y * 128, n0 = blockIdx.x * 128;
  const int wy = wid >> 1, wx = wid & 1;
  const int rq = lane & 15, kq = lane >> 4;
  f32x4 acc[4][4] = {};
  const int nkt = Kd >> 6;
  for (int kt = 0; kt < nkt; ++kt) {
    __syncthreads();  // protect LDS reuse from previous iteration's reads
    for (int iss = 0; iss < 4; ++iss) {
      int cbase = (iss * 4 + wid) * 64;  // wave-uniform LDS dest
      int c = cbase + lane;
      int row = ((c >> 7) << 4) + (c & 15);
      int col = kt * 64 + ((c >> 6) & 1) * 32 + ((c >> 4) & 3) * 8;
      gl_lds16(A + (size_t)(m0 + row) * Kd + col, (char*)Ash + cbase * 16);
      gl_lds16(B + (size_t)(n0 + row) * Kd + col, (char*)Bsh + cbase * 16);
    }
    __syncthreads();  // drains vmcnt -> LDS tiles complete
    for (int ks = 0; ks < 2; ++ks) {
      f16x8 af[4], bf[4];
      for (int t = 0; t < 4; ++t)
        af[t] = *(const f16x8*)((const char*)Ash + ((((wy * 4 + t) * 2 + ks) * 64 + lane) * 16));
      for (int u = 0; u < 4; ++u)
        bf[u] = *(const f16x8*)((const char*)Bsh + ((((wx * 4 + u) * 2 + ks) * 64 + lane) * 16));
      for (int t = 0; t < 4; ++t)
        for (int u = 0; u < 4; ++u)
          acc[t][u] = MFMA16(af[t], bf[u], acc[t][u]);
    }
  }
  // epilogue: D layout col=lane&15, row=(lane>>4)*4+reg
  for (int t = 0; t < 4; ++t) {
    int row = m0 + wy * 64 + t * 16 + 4 * kq;
    for (int u = 0; u < 4; ++u) {
      int col = n0 + wx * 64 + u * 16 + rq;
      float bv = bias[col];
      for (int rr = 0; rr < 4; ++rr) {
        float v = acc[t][u][rr] + bv;
        Co[(size_t)(row + rr) * Np + col] = (OutT)v;
      }
    }
  }
}

// ---------- normalize q,k per head + head layout; transpose v ----------
__global__ __launch_bounds__(256) void k_norm(const f16* __restrict__ qkv,
                                              f16* __restrict__ qhat,
                                              f16* __restrict__ khat,
                                              f16* __restrict__ vTt) {
  __shared__ f16 vt[64][72];
  const int blk = blockIdx.x;
  const int b = blk >> 4, lc = blk & 15;
  const int h = b & 15, n = b >> 4;
  const int tid = threadIdx.x;
  const int g4 = tid >> 2, sub = tid & 3;  // 4 lanes per row, 16 f16 each
  const int lrow = lc * 64 + g4;
  const size_t srow = ((size_t)lrow * Nb + n) * 3072;
  for (int qk = 0; qk < 2; ++qk) {
    const f16* p = qkv + srow + qk * 1024 + h * 64 + sub * 16;
    f16x8 a = *(const f16x8*)p;
    f16x8 c2 = *(const f16x8*)(p + 8);
    float ss = 0.f;
    for (int e = 0; e < 8; ++e) { float x = (float)a[e]; ss += x * x; }
    for (int e = 0; e < 8; ++e) { float x = (float)c2[e]; ss += x * x; }
    ss += __shfl_xor(ss, 1);
    ss += __shfl_xor(ss, 2);
    float sc = 1.f / fmaxf(sqrtf(ss), 1e-12f);
    f16x8 oa, ob;
    for (int e = 0; e < 8; ++e) oa[e] = (f16)((float)a[e] * sc);
    for (int e = 0; e < 8; ++e) ob[e] = (f16)((float)c2[e] * sc);
    f16* dst = (qk ? khat : qhat) + ((size_t)b * Lq + lrow) * Dd + sub * 16;
    *(f16x8*)dst = oa;
    *(f16x8*)(dst + 8) = ob;
  }
  {
    const f16* p = qkv + srow + 2048 + h * 64 + sub * 16;
    f16x8 a = *(const f16x8*)p;
    f16x8 c2 = *(const f16x8*)(p + 8);
    for (int e = 0; e < 8; ++e) vt[g4][sub * 16 + e] = a[e];
    for (int e = 0; e < 8; ++e) vt[g4][sub * 16 + 8 + e] = c2[e];
  }
  __syncthreads();
  {
    const int d = g4;
    f16x8 oa, ob;
    for (int e = 0; e < 8; ++e) oa[e] = vt[sub * 16 + e][d];
    for (int e = 0; e < 8; ++e) ob[e] = vt[sub * 16 + 8 + e][d];
    f16* dst = vTt + ((size_t)b * Dd + d) * Lq + lc * 64 + sub * 16;
    *(f16x8*)dst = oa;
    *(f16x8*)(dst + 8) = ob;
  }
}

// ---------- two-pass attention, FIXED-MAX softmax (max = ls, exact) ----------
// Logits are cosine*ls, bounded by ls => softmax with fixed shift ls is exact:
// p = exp(s*ls - ls) / sum(exp(s*ls - ls)). No row-max reduction, no online
// rescaling. Pass 1 = MFMA + exp2 + per-lane partial sums; one 4-shuffle
// reduction per row at the end. Pass 2 recomputes S, writes exact softmax
// (via LDS round-trip, dwordx4 stores), accumulates PV.
__global__ __launch_bounds__(256) void k_attn(const f16* __restrict__ qhat,
                                              const f16* __restrict__ khat,
                                              const f16* __restrict__ vTt,
                                              const float* __restrict__ lsc,
                                              const float* __restrict__ hsc,
                                              float* __restrict__ attn,
                                              f16* __restrict__ Ows) {
  __shared__ float plds[4][16 * 68];  // per-wave P tile, stride 68 (2-way = free)
  const int blk = blockIdx.x;
  const int b = blk >> 4, qc = blk & 15;
  const int h = b & 15, n = b >> 4;
  const int tid = threadIdx.x, lane = tid & 63, w = tid >> 6;
  const int rq = lane & 15, kq = lane >> 4;
  const int ib = qc * 64 + w * 16;
  const float ls = __expf(fminf(lsc[h], LOG100));
  const float hs = hsc[h];
  const float c1 = ls * LOG2E, c0 = -c1;  // exp(s*ls - ls) = exp2(s*c1 + c0)
  const f16* qb = qhat + ((size_t)b * Lq + ib) * Dd;
  f16x8 qf0 = *(const f16x8*)(qb + (size_t)rq * Dd + kq * 8);
  f16x8 qf1 = *(const f16x8*)(qb + (size_t)rq * Dd + 32 + kq * 8);
  const f16* kb = khat + (size_t)b * Lq * Dd;
  // ---- pass 1: row sums of exp (fixed shift), no shuffles in the loop ----
  float lsum[4] = {0.f, 0.f, 0.f, 0.f};
  for (int kt = 0; kt < 16; ++kt) {
    const int j0 = kt * 64;
    f32x4 s[4];
    for (int u = 0; u < 4; ++u) {
      const f16* kp = kb + (size_t)(j0 + u * 16 + rq) * Dd + kq * 8;
      f16x8 k0 = *(const f16x8*)kp;
      f16x8 k1 = *(const f16x8*)(kp + 32);
      f32x4 a = {0.f, 0.f, 0.f, 0.f};
      a = MFMA16(qf0, k0, a);
      a = MFMA16(qf1, k1, a);
      s[u] = a;
    }
    for (int rr = 0; rr < 4; ++rr) {
      float e0 = exp2f(fmaf(s[0][rr], c1, c0));
      float e1 = exp2f(fmaf(s[1][rr], c1, c0));
      float e2 = exp2f(fmaf(s[2][rr], c1, c0));
      float e3 = exp2f(fmaf(s[3][rr], c1, c0));
      lsum[rr] += (e0 + e1) + (e2 + e3);
    }
  }
  float invl[4];
  for (int rr = 0; rr < 4; ++rr) {
    float l = lsum[rr];
    l += __shfl_xor(l, 1);
    l += __shfl_xor(l, 2);
    l += __shfl_xor(l, 4);
    l += __shfl_xor(l, 8);
    invl[rr] = 1.f / l;
  }
  // ---- pass 2: recompute S, write exact softmax, accumulate PV ----
  float* pw = plds[w];
  f32x4 Oa[4] = {};
  const f16* vb = vTt + (size_t)b * Dd * Lq;
  float* ab = attn + (size_t)b * Lq * Lq;
  const int srow = lane >> 2, sc4 = lane & 3;  // store mapping: 4 lanes/row
  for (int kt = 0; kt < 16; ++kt) {
    const int j0 = kt * 64;
    f32x4 s[4];
    for (int u = 0; u < 4; ++u) {
      const f16* kp = kb + (size_t)(j0 + u * 16 + rq) * Dd + kq * 8;
      f16x8 k0 = *(const f16x8*)kp;
      f16x8 k1 = *(const f16x8*)(kp + 32);
      f32x4 a = {0.f, 0.f, 0.f, 0.f};
      a = MFMA16(qf0, k0, a);
      a = MFMA16(qf1, k1, a);
      s[u] = a;
    }
    for (int u = 0; u < 4; ++u)
      for (int rr = 0; rr < 4; ++rr) {
        float p = exp2f(fmaf(s[u][rr], c1, c0)) * invl[rr];
        pw[(4 * kq + rr) * 68 + u * 16 + rq] = p;
      }
    // vectorized attn store from the LDS tile (4 x dwordx4 per lane)
    {
      const float* lp = pw + srow * 68;
      float* gp = ab + (size_t)(ib + srow) * Lq + j0;
      for (int st = 0; st < 4; ++st) {
        int f4 = st * 4 + sc4;
        f32x4 v = *(const f32x4*)(lp + f4 * 4);
        *(f32x4*)(gp + f4 * 4) = v;
      }
    }
    // LDS round-trip: D-layout -> A-fragment layout for PV
    f16x8 pa[2];
    for (int ks = 0; ks < 2; ++ks) {
      const float* sp = pw + rq * 68 + ks * 32 + kq * 8;
      f16x8 t;
      for (int e = 0; e < 8; ++e) t[e] = (f16)sp[e];
      pa[ks] = t;
    }
    for (int t = 0; t < 4; ++t) {
      const f16* vp = vb + (size_t)(t * 16 + rq) * Lq + j0 + kq * 8;
      f16x8 v0 = *(const f16x8*)vp;
      f16x8 v1 = *(const f16x8*)(vp + 32);
      Oa[t] = MFMA16(pa[0], v0, Oa[t]);
      Oa[t] = MFMA16(pa[1], v1, Oa[t]);
    }
  }
  // epilogue: apply head_scale, store O in (L, N, C) fp16 layout
  for (int t = 0; t < 4; ++t) {
    for (int rr = 0; rr < 4; ++rr) {
      int iseq = ib + 4 * kq + rr;
      int d = t * 16 + rq;
      Ows[((size_t)iseq * Nb + n) * Cc + h * Dd + d] = (f16)(Oa[t][rr] * hs);
    }
  }
}

extern "C" void kernel_launch(void* const* d_in, const int* in_sizes, int n_in,
                              void* d_out, int out_size, void* d_ws, size_t ws_size,
                              hipStream_t stream) {
  const float* x     = (const float*)d_in[0];
  const float* w_in  = (const float*)d_in[1];
  const float* b_in  = (const float*)d_in[2];
  const float* lsc   = (const float*)d_in[3];
  const float* hsc   = (const float*)d_in[4];
  const float* w_out = (const float*)d_in[5];
  const float* b_out = (const float*)d_in[6];
  float* out  = (float*)d_out;
  float* attn = out + (size_t)Mrows * Cc;  // outputs concatenated: (out, attn)

  char* ws = (char*)d_ws;
  f16* xh   = (f16*)(ws + 0);            // 8192*1024*2   = 16,777,216
  f16* wh   = (f16*)(ws + 16777216);     // 3072*1024*2   =  6,291,456
  f16* wo   = (f16*)(ws + 23068672);     // 1024*1024*2   =  2,097,152
  f16* qkv  = (f16*)(ws + 25165824);     // 8192*3072*2   = 50,331,648
  f16* qhat = (f16*)(ws + 75497472);     // 128*1024*64*2 = 16,777,216
  f16* khat = (f16*)(ws + 92274688);
  f16* vTt  = (f16*)(ws + 109051904);
  f16* Ows  = (f16*)(ws + 125829120);    // 8192*1024*2
  if (ws_size < 142606336ull) return;    // need ~143 MB scratch

  k_cvt<<<(Mrows * Cc / 8 + 255) / 256, 256, 0, stream>>>(x, xh, Mrows * Cc / 8);
  k_cvt<<<(3072 * 1024 / 8 + 255) / 256, 256, 0, stream>>>(w_in, wh, 3072 * 1024 / 8);
  k_cvt<<<(1024 * 1024 / 8 + 255) / 256, 256, 0, stream>>>(w_out, wo, 1024 * 1024 / 8);
  k_gemm<f16><<<dim3(24, 64), 256, 0, stream>>>(xh, wh, b_in, qkv, 3072, 1024);
  k_norm<<<2048, 256, 0, stream>>>(qkv, qhat, khat, vTt);
  k_attn<<<2048, 256, 0, stream>>>(qhat, khat, vTt, lsc, hsc, attn, Ows);
  k_gemm<float><<<dim3(8, 64), 256, 0, stream>>>(Ows, wo, b_out, out, 1024, 1024);
}

// Round 7
// 864.485 us; speedup vs baseline: 1.2533x; 1.2355x over previous
//
#include <hip/hip_runtime.h>
#include <hip/hip_fp16.h>
#include <cstdint>

typedef _Float16 f16;
typedef _Float16 f16x4 __attribute__((ext_vector_type(4)));
typedef _Float16 f16x8 __attribute__((ext_vector_type(8)));
typedef float f32x4 __attribute__((ext_vector_type(4)));

#define MFMA16(a, b, c) __builtin_amdgcn_mfma_f32_16x16x32_f16(a, b, c, 0, 0, 0)

constexpr int Lq = 1024, Nb = 8, Cc = 1024, Hh = 16, Dd = 64;
constexpr int Mrows = Lq * Nb;            // 8192
constexpr float LOG100 = 4.6051701859880913680f;
constexpr float LOG2E = 1.4426950408889634f;

// ---------- async global->LDS, 16B per lane ----------
typedef const __attribute__((address_space(1))) unsigned int* gu32p;
typedef __attribute__((address_space(3))) unsigned int* lu32p;
__device__ __forceinline__ void gl_lds16(const void* g, void* l) {
  __builtin_amdgcn_global_load_lds((gu32p)g, (lu32p)l, 16, 0, 0);
}

// ---------- f32 -> f16 convert, 8 elems/thread ----------
__global__ __launch_bounds__(256) void k_cvt(const float* __restrict__ in,
                                             f16* __restrict__ out, int n8) {
  int i = blockIdx.x * blockDim.x + threadIdx.x;
  if (i >= n8) return;
  const float4* p = (const float4*)in + (size_t)i * 2;
  float4 a = p[0], b = p[1];
  f16x8 o = {(f16)a.x, (f16)a.y, (f16)a.z, (f16)a.w,
             (f16)b.x, (f16)b.y, (f16)b.z, (f16)b.w};
  *((f16x8*)out + i) = o;
}

// ---------- generic fp16 GEMM: C = A @ B^T + bias ----------
// 128x128 tile, BK=64 (2 k-subtiles of 32), 4 waves (2x2).
template <typename OutT>
__global__ __launch_bounds__(256) void k_gemm(const f16* __restrict__ A,
                                              const f16* __restrict__ B,
                                              const float* __restrict__ bias,
                                              OutT* __restrict__ Co,
                                              int Np, int Kd) {
  __shared__ f16 Ash[128 * 64];
  __shared__ f16 Bsh[128 * 64];
  const int tid = threadIdx.x, lane = tid & 63, wid = tid >> 6;
  const int m0 = blockIdx.y * 128, n0 = blockIdx.x * 128;
  const int wy = wid >> 1, wx = wid & 1;
  const int rq = lane & 15, kq = lane >> 4;
  f32x4 acc[4][4] = {};
  const int nkt = Kd >> 6;
  for (int kt = 0; kt < nkt; ++kt) {
    __syncthreads();  // protect LDS reuse from previous iteration's reads
    for (int iss = 0; iss < 4; ++iss) {
      int cbase = (iss * 4 + wid) * 64;  // wave-uniform LDS dest
      int c = cbase + lane;
      int row = ((c >> 7) << 4) + (c & 15);
      int col = kt * 64 + ((c >> 6) & 1) * 32 + ((c >> 4) & 3) * 8;
      gl_lds16(A + (size_t)(m0 + row) * Kd + col, (char*)Ash + cbase * 16);
      gl_lds16(B + (size_t)(n0 + row) * Kd + col, (char*)Bsh + cbase * 16);
    }
    __syncthreads();  // drains vmcnt -> LDS tiles complete
    for (int ks = 0; ks < 2; ++ks) {
      f16x8 af[4], bf[4];
      for (int t = 0; t < 4; ++t)
        af[t] = *(const f16x8*)((const char*)Ash + ((((wy * 4 + t) * 2 + ks) * 64 + lane) * 16));
      for (int u = 0; u < 4; ++u)
        bf[u] = *(const f16x8*)((const char*)Bsh + ((((wx * 4 + u) * 2 + ks) * 64 + lane) * 16));
      for (int t = 0; t < 4; ++t)
        for (int u = 0; u < 4; ++u)
          acc[t][u] = MFMA16(af[t], bf[u], acc[t][u]);
    }
  }
  for (int t = 0; t < 4; ++t) {
    int row = m0 + wy * 64 + t * 16 + 4 * kq;
    for (int u = 0; u < 4; ++u) {
      int col = n0 + wx * 64 + u * 16 + rq;
      float bv = bias[col];
      for (int rr = 0; rr < 4; ++rr) {
        float v = acc[t][u][rr] + bv;
        Co[(size_t)(row + rr) * Np + col] = (OutT)v;
      }
    }
  }
}

// ---------- normalize q,k per head + head layout; transpose v ----------
__global__ __launch_bounds__(256) void k_norm(const f16* __restrict__ qkv,
                                              f16* __restrict__ qhat,
                                              f16* __restrict__ khat,
                                              f16* __restrict__ vTt) {
  __shared__ f16 vt[64][72];
  const int blk = blockIdx.x;
  const int b = blk >> 4, lc = blk & 15;
  const int h = b & 15, n = b >> 4;
  const int tid = threadIdx.x;
  const int g4 = tid >> 2, sub = tid & 3;
  const int lrow = lc * 64 + g4;
  const size_t srow = ((size_t)lrow * Nb + n) * 3072;
  for (int qk = 0; qk < 2; ++qk) {
    const f16* p = qkv + srow + qk * 1024 + h * 64 + sub * 16;
    f16x8 a = *(const f16x8*)p;
    f16x8 c2 = *(const f16x8*)(p + 8);
    float ss = 0.f;
    for (int e = 0; e < 8; ++e) { float x = (float)a[e]; ss += x * x; }
    for (int e = 0; e < 8; ++e) { float x = (float)c2[e]; ss += x * x; }
    ss += __shfl_xor(ss, 1);
    ss += __shfl_xor(ss, 2);
    float sc = 1.f / fmaxf(sqrtf(ss), 1e-12f);
    f16x8 oa, ob;
    for (int e = 0; e < 8; ++e) oa[e] = (f16)((float)a[e] * sc);
    for (int e = 0; e < 8; ++e) ob[e] = (f16)((float)c2[e] * sc);
    f16* dst = (qk ? khat : qhat) + ((size_t)b * Lq + lrow) * Dd + sub * 16;
    *(f16x8*)dst = oa;
    *(f16x8*)(dst + 8) = ob;
  }
  {
    const f16* p = qkv + srow + 2048 + h * 64 + sub * 16;
    f16x8 a = *(const f16x8*)p;
    f16x8 c2 = *(const f16x8*)(p + 8);
    for (int e = 0; e < 8; ++e) vt[g4][sub * 16 + e] = a[e];
    for (int e = 0; e < 8; ++e) vt[g4][sub * 16 + 8 + e] = c2[e];
  }
  __syncthreads();
  {
    const int d = g4;
    f16x8 oa, ob;
    for (int e = 0; e < 8; ++e) oa[e] = vt[sub * 16 + e][d];
    for (int e = 0; e < 8; ++e) ob[e] = vt[sub * 16 + 8 + e][d];
    f16* dst = vTt + ((size_t)b * Dd + d) * Lq + lc * 64 + sub * 16;
    *(f16x8*)dst = oa;
    *(f16x8*)(dst + 8) = ob;
  }
}

// ---------- attention v3: LDS-staged K/V, swapped QK^T, two-pass ----------
// Block = 4 waves, 64 q-rows (16/wave). Swapped MFMA: s = mfma(K, Q) so lane
// (rq,kq) holds S[q=rq][kv=j0+u*16+4kq+rr] (one q-row per lane).
// Pass 1: stage K,V -> QK -> exp (fixed shift ls) -> lsum (per-lane) ->
//         P(f16, unnorm) via tiny chunk-linear LDS tile -> PV accumulate.
// Pass 2: stage K -> QK -> exp*invl -> direct f32x4 store of softmax. No LDS.
// K/V LDS layout is chunk-linear in fragment-read order => linear ds_read_b128.
__global__ __launch_bounds__(256) void k_attn(const f16* __restrict__ qhat,
                                              const f16* __restrict__ khat,
                                              const f16* __restrict__ vTt,
                                              const float* __restrict__ lsc,
                                              const float* __restrict__ hsc,
                                              float* __restrict__ attn,
                                              f16* __restrict__ Ows) {
  __shared__ f16 Kst[4096];        // 64kv x 64d chunk-linear: c = u*128+h*64+kq*16+rq
  __shared__ f16 Vst[4096];        // 64d x 64kv chunk-linear: c = t*128+ks*64+kq*16+rq
  __shared__ f16 Pst[4][1024];     // per-wave 16q x 64kv chunk-linear: c = ks*64+kq*16+rq
  const int blk = blockIdx.x;
  const int b = blk >> 4, qc = blk & 15;
  const int h = b & 15, n = b >> 4;
  const int tid = threadIdx.x, lane = tid & 63, w = tid >> 6;
  const int rq = lane & 15, kq = lane >> 4;
  const int ib = qc * 64 + w * 16;
  const float ls = __expf(fminf(lsc[h], LOG100));
  const float hs = hsc[h];
  const float c1 = ls * LOG2E, c0 = -c1;  // exp(s*ls - ls) = exp2(s*c1 + c0)
  const f16* qb = qhat + ((size_t)b * Lq + ib) * Dd;
  f16x8 qf0 = *(const f16x8*)(qb + (size_t)rq * Dd + kq * 8);
  f16x8 qf1 = *(const f16x8*)(qb + (size_t)rq * Dd + 32 + kq * 8);
  const f16* kb = khat + (size_t)b * Lq * Dd;
  const f16* vb = vTt + (size_t)b * Dd * Lq;
  f16* Pw = Pst[w];

  // ---- pass 1 ----
  float lsum = 0.f;
  f32x4 Oa[4] = {};
  for (int kt = 0; kt < 16; ++kt) {
    const int j0 = kt * 64;
    __syncthreads();  // protect LDS from previous iteration's readers
    for (int iss = 0; iss < 2; ++iss) {
      int cbase = (iss * 4 + w) * 64;   // wave-uniform LDS chunk base
      int c = cbase + lane;
      int rq_ = c & 15, kq_ = (c >> 4) & 3, h_ = (c >> 6) & 1, u_ = c >> 7;
      gl_lds16(kb + (size_t)(j0 + u_ * 16 + rq_) * Dd + h_ * 32 + kq_ * 8,
               (char*)Kst + cbase * 16);
      gl_lds16(vb + (size_t)(u_ * 16 + rq_) * Lq + j0 + h_ * 32 + kq_ * 8,
               (char*)Vst + cbase * 16);
    }
    __syncthreads();  // drain -> tiles ready
    f32x4 s[4];
    for (int u = 0; u < 4; ++u) {
      f16x8 k0 = *(const f16x8*)(Kst + (u * 128 + lane) * 8);
      f16x8 k1 = *(const f16x8*)(Kst + (u * 128 + 64 + lane) * 8);
      f32x4 a = {0.f, 0.f, 0.f, 0.f};
      a = MFMA16(k0, qf0, a);
      a = MFMA16(k1, qf1, a);
      s[u] = a;
    }
    for (int u = 0; u < 4; ++u) {
      f16x4 t4;
      for (int rr = 0; rr < 4; ++rr) {
        float e = exp2f(fmaf(s[u][rr], c1, c0));  // unnormalized, in (0,1]
        lsum += e;
        t4[rr] = (f16)e;
      }
      int cw = (u >> 1) * 64 + ((2 * u + (kq >> 1)) & 3) * 16 + rq;
      *(f16x4*)(Pw + cw * 8 + (kq & 1) * 4) = t4;
    }
    f16x8 pa0 = *(const f16x8*)(Pw + (kq * 16 + rq) * 8);
    f16x8 pa1 = *(const f16x8*)(Pw + (64 + kq * 16 + rq) * 8);
    for (int t = 0; t < 4; ++t) {
      f16x8 v0 = *(const f16x8*)(Vst + (t * 128 + lane) * 8);
      f16x8 v1 = *(const f16x8*)(Vst + (t * 128 + 64 + lane) * 8);
      Oa[t] = MFMA16(pa0, v0, Oa[t]);
      Oa[t] = MFMA16(pa1, v1, Oa[t]);
    }
  }
  lsum += __shfl_xor(lsum, 16);
  lsum += __shfl_xor(lsum, 32);
  const float invl = 1.f / lsum;

  // ---- pass 2: streaming softmax store (no LDS besides K staging) ----
  float* ab = attn + (size_t)b * Lq * Lq + (size_t)(ib + rq) * Lq;
  for (int kt = 0; kt < 16; ++kt) {
    const int j0 = kt * 64;
    __syncthreads();
    {
      int cbase = w * 64 + ((lane >> 5) ? 1024 : 0);  // 2 issues worth in one? no:
    }
    // stage K: 8 x 64-chunk groups over 4 waves = 2 issues/wave
    for (int iss = 0; iss < 2; ++iss) {
      int cbase = (iss * 4 + w) * 64;
      int c = cbase + lane;
      int rq_ = c & 15, kq_ = (c >> 4) & 3, h_ = (c >> 6) & 1, u_ = c >> 7;
      gl_lds16(kb + (size_t)(j0 + u_ * 16 + rq_) * Dd + h_ * 32 + kq_ * 8,
               (char*)Kst + cbase * 16);
    }
    __syncthreads();
    f32x4 s[4];
    for (int u = 0; u < 4; ++u) {
      f16x8 k0 = *(const f16x8*)(Kst + (u * 128 + lane) * 8);
      f16x8 k1 = *(const f16x8*)(Kst + (u * 128 + 64 + lane) * 8);
      f32x4 a = {0.f, 0.f, 0.f, 0.f};
      a = MFMA16(k0, qf0, a);
      a = MFMA16(k1, qf1, a);
      s[u] = a;
    }
    for (int u = 0; u < 4; ++u) {
      f32x4 p;
      for (int rr = 0; rr < 4; ++rr)
        p[rr] = exp2f(fmaf(s[u][rr], c1, c0)) * invl;
      *(f32x4*)(ab + j0 + u * 16 + 4 * kq) = p;
    }
  }

  // ---- epilogue: O = Oa * invl(row) * hs ----
  float invlO[4];
  for (int rr = 0; rr < 4; ++rr) invlO[rr] = __shfl(invl, 4 * kq + rr);
  for (int t = 0; t < 4; ++t) {
    for (int rr = 0; rr < 4; ++rr) {
      int iseq = ib + 4 * kq + rr;
      int d = t * 16 + rq;
      Ows[((size_t)iseq * Nb + n) * Cc + h * Dd + d] = (f16)(Oa[t][rr] * invlO[rr] * hs);
    }
  }
}

extern "C" void kernel_launch(void* const* d_in, const int* in_sizes, int n_in,
                              void* d_out, int out_size, void* d_ws, size_t ws_size,
                              hipStream_t stream) {
  const float* x     = (const float*)d_in[0];
  const float* w_in  = (const float*)d_in[1];
  const float* b_in  = (const float*)d_in[2];
  const float* lsc   = (const float*)d_in[3];
  const float* hsc   = (const float*)d_in[4];
  const float* w_out = (const float*)d_in[5];
  const float* b_out = (const float*)d_in[6];
  float* out  = (float*)d_out;
  float* attn = out + (size_t)Mrows * Cc;  // outputs concatenated: (out, attn)

  char* ws = (char*)d_ws;
  f16* xh   = (f16*)(ws + 0);
  f16* wh   = (f16*)(ws + 16777216);
  f16* wo   = (f16*)(ws + 23068672);
  f16* qkv  = (f16*)(ws + 25165824);
  f16* qhat = (f16*)(ws + 75497472);
  f16* khat = (f16*)(ws + 92274688);
  f16* vTt  = (f16*)(ws + 109051904);
  f16* Ows  = (f16*)(ws + 125829120);
  if (ws_size < 142606336ull) return;

  k_cvt<<<(Mrows * Cc / 8 + 255) / 256, 256, 0, stream>>>(x, xh, Mrows * Cc / 8);
  k_cvt<<<(3072 * 1024 / 8 + 255) / 256, 256, 0, stream>>>(w_in, wh, 3072 * 1024 / 8);
  k_cvt<<<(1024 * 1024 / 8 + 255) / 256, 256, 0, stream>>>(w_out, wo, 1024 * 1024 / 8);
  k_gemm<f16><<<dim3(24, 64), 256, 0, stream>>>(xh, wh, b_in, qkv, 3072, 1024);
  k_norm<<<2048, 256, 0, stream>>>(qkv, qhat, khat, vTt);
  k_attn<<<2048, 256, 0, stream>>>(qhat, khat, vTt, lsc, hsc, attn, Ows);
  k_gemm<float><<<dim3(8, 64), 256, 0, stream>>>(Ows, wo, b_out, out, 1024, 1024);
}